// Round 1
// baseline (298.356 us; speedup 1.0000x reference)
//
#include <hip/hip_runtime.h>
#include <math.h>

#define N_BINS_MAX 1024
#define EPS 1e-4f

__global__ __launch_bounds__(256) void pm_kernel(
    const float* __restrict__ bin_centers, int n_bins,
    const int* __restrict__ idx,
    const float* __restrict__ lb,
    const float* __restrict__ ub,
    float* __restrict__ out,
    long long n_rows)
{
    __shared__ float tab0[N_BINS_MAX];
    __shared__ float tab1[N_BINS_MAX];
    __shared__ float tab2[N_BINS_MAX];

    const float lb0 = lb[0], lb1 = lb[1], lb2 = lb[2];
    const float ub0 = ub[0], ub1 = ub[1], ub2 = ub[2];
    const float r0 = 1.0f / (ub0 - lb0 + EPS);
    const float r1 = 1.0f / (ub1 - lb1 + EPS);
    const float r2 = 1.0f / (ub2 - lb2 + EPS);

    // Build the per-column sigmoid LUTs: 1024 bins x 3 columns = 12 KB LDS.
    for (int i = threadIdx.x; i < n_bins; i += blockDim.x) {
        float c = bin_centers[i];
        float logit = logf(c / (1.0f - c));
        float x0 = (ub0 - logit) * r0;
        float x1 = (ub1 - logit) * r1;
        float x2 = (ub2 - logit) * r2;
        tab0[i] = 1.0f / (1.0f + expf(-x0));
        tab1[i] = 1.0f / (1.0f + expf(-x1));
        tab2[i] = 1.0f / (1.0f + expf(-x2));
    }
    __syncthreads();

    // Hot loop: 4 rows per thread. Row r uses ints [3r, 3r+2]; a quad of 4
    // rows is 12 consecutive ints = three aligned int4 loads (48 B/lane,
    // fully consumed -> 100% cache-line utilization), one float4 store.
    const long long n_quads = n_rows >> 2;
    const int4* __restrict__ idx4 = (const int4*)idx;
    float4* __restrict__ out4 = (float4*)out;
    const long long stride = (long long)gridDim.x * blockDim.x;

    for (long long q = (long long)blockIdx.x * blockDim.x + threadIdx.x;
         q < n_quads; q += stride) {
        int4 a = idx4[3 * q + 0];
        int4 b = idx4[3 * q + 1];
        int4 c = idx4[3 * q + 2];
        float4 r;
        r.x = tab0[a.x] * tab1[a.y] * tab2[a.z];
        r.y = tab0[a.w] * tab1[b.x] * tab2[b.y];
        r.z = tab0[b.z] * tab1[b.w] * tab2[c.x];
        r.w = tab0[c.y] * tab1[c.z] * tab2[c.w];
        out4[q] = r;
    }

    // Tail rows (n_rows % 4) — none for the bench shape, kept for generality.
    const long long tail_start = n_quads << 2;
    for (long long row = tail_start + (long long)blockIdx.x * blockDim.x + threadIdx.x;
         row < n_rows; row += stride) {
        int i0 = idx[3 * row + 0];
        int i1 = idx[3 * row + 1];
        int i2 = idx[3 * row + 2];
        out[row] = tab0[i0] * tab1[i1] * tab2[i2];
    }
}

extern "C" void kernel_launch(void* const* d_in, const int* in_sizes, int n_in,
                              void* d_out, int out_size, void* d_ws, size_t ws_size,
                              hipStream_t stream) {
    const float* bin_centers = (const float*)d_in[0];
    const int*   idx         = (const int*)d_in[1];
    const float* lb          = (const float*)d_in[2];
    const float* ub          = (const float*)d_in[3];
    // d_in[4] = operator_number (unused by the math)
    float* out = (float*)d_out;

    int n_bins = in_sizes[0];
    long long n_rows = (long long)in_sizes[1] / 3;

    const int block = 256;
    long long n_quads = n_rows >> 2;
    long long want = (n_quads + block - 1) / block;
    if (want < 1) want = 1;
    int grid = (int)((want > 16384) ? 16384 : want);

    pm_kernel<<<grid, block, 0, stream>>>(bin_centers, n_bins, idx, lb, ub, out, n_rows);
}